// Round 6
// baseline (769.353 us; speedup 1.0000x reference)
//
#include <hip/hip_runtime.h>
#include <hip/hip_bf16.h>
#include <cstdint>
#include <cstddef>

#define S_LEN 512
#define BATCH 32
#define EDIM  300
#define KPAD  320   // single f16 pass
#define HDIM  128
#define NGATE 512   // 4*H
#define NCOLS 1024  // fwd 512 + bwd 512

typedef float    f2   __attribute__((ext_vector_type(2)));
typedef float    f4v  __attribute__((ext_vector_type(4)));
typedef _Float16 h2   __attribute__((ext_vector_type(2)));
typedef _Float16 h4   __attribute__((ext_vector_type(4)));
typedef _Float16 half8 __attribute__((ext_vector_type(8)));

// ---------------------------------------------------------------------------
// Kernel 1 (fused): embeddings -> Xcat (f16), and Wih -> Wcat (f16).
// (unchanged from R5, verified)
// ---------------------------------------------------------------------------
__global__ void embed_wcat(const int* __restrict__ word_ids,
                           const int* __restrict__ deps_ids,
                           const float* __restrict__ word_table,
                           const float* __restrict__ dep_table,
                           const float* __restrict__ Wih_f,
                           const float* __restrict__ Wih_b,
                           _Float16* __restrict__ Xcat,
                           _Float16* __restrict__ Wcat) {
    int blk = blockIdx.x;
    if (blk >= BATCH * S_LEN) {
        int n = blk - BATCH * S_LEN;
        const float* src = (n < NGATE) ? (Wih_f + (size_t)n * EDIM)
                                       : (Wih_b + (size_t)(n - NGATE) * EDIM);
        _Float16* wr = Wcat + (size_t)n * KPAD;
        for (int e = threadIdx.x; e < KPAD; e += 128)
            wr[e] = (_Float16)((e < EDIM) ? src[e] : 0.f);
        return;
    }
    int pos = blk;
    int b = pos >> 9, s = pos & (S_LEN - 1);
    int wid = word_ids[b * 3 * S_LEN + S_LEN + s];
    const int* dp = deps_ids + (size_t)pos * 8;
    int ids[8];
    int cnt = 0;
#pragma unroll
    for (int d = 0; d < 8; ++d) {
        int id = dp[d];
        ids[d] = id;
        cnt += (id != 0 && id != 1) ? 1 : 0;
    }
    float inv = 0.5f / (float)((cnt > 0) ? cnt : 1);
    const float* wr = word_table + (size_t)wid * EDIM;
    _Float16* xr = Xcat + (size_t)pos * KPAD;
    for (int e = threadIdx.x; e < KPAD; e += 128) {
        float v = 0.f;
        if (e < EDIM) {
            float w = wr[e];
            float dsum = 0.f;
#pragma unroll
            for (int d = 0; d < 8; ++d) {
                if (ids[d] != 0 && ids[d] != 1) dsum += dep_table[ids[d] * EDIM + e];
            }
            v = (cnt > 0) ? (0.5f * w + dsum * inv) : w;
        }
        xr[e] = (_Float16)v;
    }
}

// ---------------------------------------------------------------------------
// Kernel 2: MFMA GEMM, f16 single-pass (unchanged from R5, verified).
// ---------------------------------------------------------------------------
#define LSTR 40
__global__ __launch_bounds__(256) void gemm_mfma(
        const _Float16* __restrict__ Xcat,
        const _Float16* __restrict__ Wcat,
        const float* __restrict__ b_f, const float* __restrict__ b_b,
        float* __restrict__ pre) {
    __shared__ _Float16 Asub[128 * LSTR];
    __shared__ _Float16 Bsub[128 * LSTR];
    int tid = threadIdx.x;
    int wave = tid >> 6, lane = tid & 63;
    int lid = lane & 15, quad = lane >> 4;
    int m0 = blockIdx.x * 128, n0 = blockIdx.y * 128;
    int wm = (wave >> 1) * 64, wn = (wave & 1) * 64;

    f4v acc[4][4];
#pragma unroll
    for (int i = 0; i < 4; ++i)
#pragma unroll
        for (int j = 0; j < 4; ++j) acc[i][j] = (f4v)0.f;

    float bias[4];
#pragma unroll
    for (int nt = 0; nt < 4; ++nt) {
        int n = n0 + wn + nt * 16 + lid;
        bias[nt] = (n < NGATE) ? b_f[n] : b_b[n - NGATE];
    }

    int c0 = tid, c1 = tid + 256;
    const _Float16* aptr0 = Xcat + (size_t)(m0 + (c0 >> 2)) * KPAD + (c0 & 3) * 8;
    const _Float16* aptr1 = Xcat + (size_t)(m0 + (c1 >> 2)) * KPAD + (c1 & 3) * 8;
    const _Float16* bptr0 = Wcat + (size_t)(n0 + (c0 >> 2)) * KPAD + (c0 & 3) * 8;
    const _Float16* bptr1 = Wcat + (size_t)(n0 + (c1 >> 2)) * KPAD + (c1 & 3) * 8;
    int la0 = (c0 >> 2) * LSTR + (c0 & 3) * 8;
    int la1 = (c1 >> 2) * LSTR + (c1 & 3) * 8;

    half8 ra0 = *(const half8*)(aptr0);
    half8 ra1 = *(const half8*)(aptr1);
    half8 rb0 = *(const half8*)(bptr0);
    half8 rb1 = *(const half8*)(bptr1);

    for (int k0 = 0; k0 < KPAD; k0 += 32) {
        __syncthreads();
        *(half8*)&Asub[la0] = ra0;
        *(half8*)&Asub[la1] = ra1;
        *(half8*)&Bsub[la0] = rb0;
        *(half8*)&Bsub[la1] = rb1;
        __syncthreads();
        if (k0 + 32 < KPAD) {
            ra0 = *(const half8*)(aptr0 + k0 + 32);
            ra1 = *(const half8*)(aptr1 + k0 + 32);
            rb0 = *(const half8*)(bptr0 + k0 + 32);
            rb1 = *(const half8*)(bptr1 + k0 + 32);
        }
        half8 aF[4], bF[4];
#pragma unroll
        for (int mt = 0; mt < 4; ++mt)
            aF[mt] = *(const half8*)&Asub[(wm + mt * 16 + lid) * LSTR + quad * 8];
#pragma unroll
        for (int nt = 0; nt < 4; ++nt)
            bF[nt] = *(const half8*)&Bsub[(wn + nt * 16 + lid) * LSTR + quad * 8];
#pragma unroll
        for (int mt = 0; mt < 4; ++mt)
#pragma unroll
            for (int nt = 0; nt < 4; ++nt)
                acc[mt][nt] = __builtin_amdgcn_mfma_f32_16x16x32_f16(
                    aF[mt], bF[nt], acc[mt][nt], 0, 0, 0);
    }

#pragma unroll
    for (int mt = 0; mt < 4; ++mt)
#pragma unroll
        for (int nt = 0; nt < 4; ++nt) {
            int n = n0 + wn + nt * 16 + lid;
#pragma unroll
            for (int r = 0; r < 4; ++r) {
                int m = m0 + wm + mt * 16 + quad * 4 + r;
                pre[(size_t)m * NCOLS + n] = acc[mt][nt][r] + bias[nt];
            }
        }
}

// ---------------------------------------------------------------------------
// Kernel 3: LSTM recurrence v10 — 16-problem batched MFMA recurrence.
// 4 blocks x 512 threads (8 waves, 2/SIMD).  Block blk: dir = blk>>1,
// problems b = (blk&1)*16 + lid  (16 same-direction recurrences = the 16
// MFMA B-columns; all run 512 lock-stepped steps).
// Per step: D[512 gate-rows][16 probs] = Whh(512x128) x H(128x16):
//   wave wv owns h-range 16wv..16wv+15; its 4 m-tiles = the 4 gate types
//   (i,f,g,o) of that range -> 16 MFMA/wave (4 tau x 4 ktile).
// A-frag (verified gemm pattern, lane lid = row): afr[tau][kt] =
//   Whh[tau*128+16wv+lid][32kt+8quad+e] -- persistent, 64 VGPR.
// B-frag (lane lid = col = problem): Hs[p=lid][k=32kt+8quad+e] f16,
//   row stride 304B (pad: quarter-wave start banks = all 8 4-bank groups
//   -> optimal 2-phase ds_read_b128).
// D: lane (lid,quad) reg r = gates i/f/g/o of (p=lid, h=16wv+4quad+r)
//   -> c/h update fully lane-local (NO cross-lane at all).
// Hs double-buffered (even: read0/write1) -> no WAR-window assumption;
// one lgkm-only barrier per step.  Gate pre-acts: 16 scalar loads/lane
// with imm offsets, 2-step pipeline (pnA/pnB), issued right after use.
// ---------------------------------------------------------------------------
#define HSTR 304  // bytes per Hs row (128 f16 + 24 pad)
__global__ __launch_bounds__(512, 2) void lstm_rec(
        const float* __restrict__ pre,
        const float* __restrict__ Whh_f, const float* __restrict__ Whh_b,
        float* __restrict__ pooled) {
    __shared__ __align__(16) _Float16 Hs[2 * 16 * (HSTR / 2)];
    int t = threadIdx.x;
    int lane = t & 63;
    int wv = t >> 6;                 // 0..7 : h-range 16wv..16wv+15
    int lid = lane & 15;             // problem index within block
    int quad = lane >> 4;
    int dir = blockIdx.x >> 1;
    int b = (blockIdx.x & 1) * 16 + lid;
    const float* Whh = dir ? Whh_b : Whh_f;

    // persistent A-fragments: 16 x half8 = 64 VGPR
    half8 afr[4][4];
#pragma unroll
    for (int tau = 0; tau < 4; ++tau)
#pragma unroll
        for (int kt = 0; kt < 4; ++kt) {
            const float* rp = Whh + (size_t)(tau * HDIM + 16 * wv + lid) * HDIM
                            + 32 * kt + 8 * quad;
            half8 hv;
#pragma unroll
            for (int e = 0; e < 8; ++e) hv[e] = (_Float16)rp[e];
            afr[tau][kt] = hv;
        }

    // zero both Hs buffers (h_0 = 0)
    for (int i = t; i < 2 * 16 * (HSTR / 4); i += 512) ((uint*)Hs)[i] = 0u;

    const char* hrd0 = (const char*)Hs + lid * HSTR + 16 * quad;
    const char* hrd1 = hrd0 + 16 * HSTR;
    char* hwr0 = (char*)Hs + lid * HSTR + (16 * wv + 4 * quad) * 2;
    char* hwr1 = hwr0 + 16 * HSTR;

    const f4v zero4 = (f4v)0.f;
    float cc[4] = {0.f, 0.f, 0.f, 0.f};
    float hm[4] = {-1e30f, -1e30f, -1e30f, -1e30f};

    int s0 = dir ? (S_LEN - 1) : 0;
    long pstride = dir ? -(long)NCOLS : (long)NCOLS;
    const float* pf = pre + (size_t)(b * S_LEN + s0) * NCOLS + dir * NGATE
                    + 16 * wv + 4 * quad;

    float pnA[16], pnB[16];
#pragma unroll
    for (int j = 0; j < 16; ++j) pnA[j] = pf[(j >> 2) * HDIM + (j & 3)];
    pf += pstride;
#pragma unroll
    for (int j = 0; j < 16; ++j) pnB[j] = pf[(j >> 2) * HDIM + (j & 3)];
    pf += pstride;

    asm volatile("s_waitcnt lgkmcnt(0)\n\ts_barrier" ::: "memory");

#define LSTM_STEP(PN, HRD, HWR, DOLOAD)                                       \
    do {                                                                      \
        half8 bf0 = *(const half8*)(HRD);                                     \
        half8 bf1 = *(const half8*)(HRD + 64);                                \
        half8 bf2 = *(const half8*)(HRD + 128);                               \
        half8 bf3 = *(const half8*)(HRD + 192);                               \
        f4v acc[4];                                                           \
        _Pragma("unroll")                                                     \
        for (int tau = 0; tau < 4; ++tau) {                                   \
            f4v a = __builtin_amdgcn_mfma_f32_16x16x32_f16(                   \
                afr[tau][0], bf0, zero4, 0, 0, 0);                            \
            a = __builtin_amdgcn_mfma_f32_16x16x32_f16(                       \
                afr[tau][1], bf1, a, 0, 0, 0);                                \
            a = __builtin_amdgcn_mfma_f32_16x16x32_f16(                       \
                afr[tau][2], bf2, a, 0, 0, 0);                                \
            a = __builtin_amdgcn_mfma_f32_16x16x32_f16(                       \
                afr[tau][3], bf3, a, 0, 0, 0);                                \
            acc[tau] = a;                                                     \
        }                                                                     \
        float g[4][4];                                                        \
        _Pragma("unroll")                                                     \
        for (int tau = 0; tau < 4; ++tau)                                     \
            _Pragma("unroll")                                                 \
            for (int r = 0; r < 4; ++r)                                       \
                g[tau][r] = acc[tau][r] + PN[tau * 4 + r];                    \
        if (DOLOAD) {                                                         \
            _Pragma("unroll")                                                 \
            for (int j = 0; j < 16; ++j)                                      \
                PN[j] = pf[(j >> 2) * HDIM + (j & 3)];                        \
        }                                                                     \
        pf += pstride;                                                        \
        float hv[4];                                                          \
        _Pragma("unroll")                                                     \
        for (int r = 0; r < 4; ++r) {                                         \
            float ei = __expf(-g[0][r]);                                      \
            float ii = __builtin_amdgcn_rcpf(1.f + ei);                       \
            float ef = __expf(-g[1][r]);                                      \
            float ff = __builtin_amdgcn_rcpf(1.f + ef);                       \
            float eg = __expf(-2.f * g[2][r]);                                \
            float tg = fmaf(__builtin_amdgcn_rcpf(1.f + eg), 2.f, -1.f);      \
            float eo = __expf(-g[3][r]);                                      \
            float oo = __builtin_amdgcn_rcpf(1.f + eo);                       \
            cc[r] = fmaf(ff, cc[r], ii * tg);                                 \
            float et = __expf(-2.f * cc[r]);                                  \
            float th = fmaf(__builtin_amdgcn_rcpf(1.f + et), 2.f, -1.f);      \
            float hh = oo * th;                                               \
            hm[r] = fmaxf(hm[r], hh);                                         \
            hv[r] = hh;                                                       \
        }                                                                     \
        h4 hwv;                                                               \
        hwv[0] = (_Float16)hv[0];                                             \
        hwv[1] = (_Float16)hv[1];                                             \
        hwv[2] = (_Float16)hv[2];                                             \
        hwv[3] = (_Float16)hv[3];                                             \
        *(h4*)(HWR) = hwv;                                                    \
        asm volatile("s_waitcnt lgkmcnt(0)\n\ts_barrier" ::: "memory");       \
    } while (0)

    for (int i = 0; i < S_LEN / 2; ++i) {
        bool doload = (i < S_LEN / 2 - 1);
        LSTM_STEP(pnA, hrd0, hwr1, doload);   // even step: read buf0, write buf1
        LSTM_STEP(pnB, hrd1, hwr0, doload);   // odd step:  read buf1, write buf0
    }
#undef LSTM_STEP

#pragma unroll
    for (int r = 0; r < 4; ++r)
        pooled[b * 256 + dir * HDIM + 16 * wv + 4 * quad + r] = hm[r];
}

// ---------------------------------------------------------------------------
// Kernel 4: classifier (unchanged)
// ---------------------------------------------------------------------------
__global__ void cls_kernel(const float* __restrict__ pooled,
                           const float* __restrict__ W_cls,
                           const float* __restrict__ b_cls,
                           float* __restrict__ out) {
    int i = threadIdx.x;
    if (i < BATCH * 5) {
        int b = i / 5, l = i % 5;
        float acc = b_cls[l];
        const float* p = pooled + b * 256;
        const float* w = W_cls + l * 256;
#pragma unroll 8
        for (int j = 0; j < 256; ++j) acc = fmaf(p[j], w[j], acc);
        out[i] = acc;
    }
}

// ---------------------------------------------------------------------------
extern "C" void kernel_launch(void* const* d_in, const int* in_sizes, int n_in,
                              void* d_out, int out_size, void* d_ws, size_t ws_size,
                              hipStream_t stream) {
    const int*   word_ids   = (const int*)d_in[0];
    const int*   deps_ids   = (const int*)d_in[1];
    const float* word_table = (const float*)d_in[2];
    const float* dep_table  = (const float*)d_in[3];
    const float* Wih_f      = (const float*)d_in[4];
    const float* Whh_f      = (const float*)d_in[5];
    const float* b_f        = (const float*)d_in[6];
    const float* Wih_b      = (const float*)d_in[7];
    const float* Whh_b      = (const float*)d_in[8];
    const float* b_b        = (const float*)d_in[9];
    const float* W_cls      = (const float*)d_in[10];
    const float* b_cls      = (const float*)d_in[11];
    float* out = (float*)d_out;

    float*     pre    = (float*)d_ws;
    float*     pooled = pre + (size_t)BATCH * S_LEN * NCOLS;
    _Float16*  Xcat   = (_Float16*)(pooled + BATCH * 256);
    _Float16*  Wcat   = Xcat + (size_t)BATCH * S_LEN * KPAD;

    embed_wcat<<<BATCH * S_LEN + NCOLS, 128, 0, stream>>>(
        word_ids, deps_ids, word_table, dep_table, Wih_f, Wih_b, Xcat, Wcat);
    gemm_mfma<<<dim3(128, 8), 256, 0, stream>>>(Xcat, Wcat, b_f, b_b, pre);
    lstm_rec<<<4, 512, 0, stream>>>(pre, Whh_f, Whh_b, pooled);
    cls_kernel<<<1, 192, 0, stream>>>(pooled, W_cls, b_cls, out);
}

// Round 7
// 601.708 us; speedup vs baseline: 1.2786x; 1.2786x over previous
//
#include <hip/hip_runtime.h>
#include <hip/hip_bf16.h>
#include <cstdint>
#include <cstddef>

#define S_LEN 512
#define BATCH 32
#define EDIM  300
#define KPAD  320   // single f16 pass
#define HDIM  128
#define NGATE 512   // 4*H
#define NCOLS 1024  // fwd 512 + bwd 512

typedef float    f2   __attribute__((ext_vector_type(2)));
typedef float    f4v  __attribute__((ext_vector_type(4)));
typedef _Float16 h2   __attribute__((ext_vector_type(2)));
typedef _Float16 h4   __attribute__((ext_vector_type(4)));
typedef _Float16 half8 __attribute__((ext_vector_type(8)));

// DPP cross-lane move (VALU pipe). 0x128 = row_ror:8 (verified).
template <int CTRL>
__device__ __forceinline__ float dpp_mov(float x) {
    int r = __builtin_amdgcn_update_dpp(0, __float_as_int(x), CTRL, 0xF, 0xF, true);
    return __int_as_float(r);
}

// ---------------------------------------------------------------------------
// Kernel 1 (fused): embeddings -> Xcat (f16), and Wih -> Wcat (f16).
// (unchanged from R5, verified)
// ---------------------------------------------------------------------------
__global__ void embed_wcat(const int* __restrict__ word_ids,
                           const int* __restrict__ deps_ids,
                           const float* __restrict__ word_table,
                           const float* __restrict__ dep_table,
                           const float* __restrict__ Wih_f,
                           const float* __restrict__ Wih_b,
                           _Float16* __restrict__ Xcat,
                           _Float16* __restrict__ Wcat) {
    int blk = blockIdx.x;
    if (blk >= BATCH * S_LEN) {
        int n = blk - BATCH * S_LEN;
        const float* src = (n < NGATE) ? (Wih_f + (size_t)n * EDIM)
                                       : (Wih_b + (size_t)(n - NGATE) * EDIM);
        _Float16* wr = Wcat + (size_t)n * KPAD;
        for (int e = threadIdx.x; e < KPAD; e += 128)
            wr[e] = (_Float16)((e < EDIM) ? src[e] : 0.f);
        return;
    }
    int pos = blk;
    int b = pos >> 9, s = pos & (S_LEN - 1);
    int wid = word_ids[b * 3 * S_LEN + S_LEN + s];
    const int* dp = deps_ids + (size_t)pos * 8;
    int ids[8];
    int cnt = 0;
#pragma unroll
    for (int d = 0; d < 8; ++d) {
        int id = dp[d];
        ids[d] = id;
        cnt += (id != 0 && id != 1) ? 1 : 0;
    }
    float inv = 0.5f / (float)((cnt > 0) ? cnt : 1);
    const float* wr = word_table + (size_t)wid * EDIM;
    _Float16* xr = Xcat + (size_t)pos * KPAD;
    for (int e = threadIdx.x; e < KPAD; e += 128) {
        float v = 0.f;
        if (e < EDIM) {
            float w = wr[e];
            float dsum = 0.f;
#pragma unroll
            for (int d = 0; d < 8; ++d) {
                if (ids[d] != 0 && ids[d] != 1) dsum += dep_table[ids[d] * EDIM + e];
            }
            v = (cnt > 0) ? (0.5f * w + dsum * inv) : w;
        }
        xr[e] = (_Float16)v;
    }
}

// ---------------------------------------------------------------------------
// Kernel 2: MFMA GEMM, f16 single-pass (unchanged from R5, verified).
// ---------------------------------------------------------------------------
#define LSTR 40
__global__ __launch_bounds__(256) void gemm_mfma(
        const _Float16* __restrict__ Xcat,
        const _Float16* __restrict__ Wcat,
        const float* __restrict__ b_f, const float* __restrict__ b_b,
        float* __restrict__ pre) {
    __shared__ _Float16 Asub[128 * LSTR];
    __shared__ _Float16 Bsub[128 * LSTR];
    int tid = threadIdx.x;
    int wave = tid >> 6, lane = tid & 63;
    int lid = lane & 15, quad = lane >> 4;
    int m0 = blockIdx.x * 128, n0 = blockIdx.y * 128;
    int wm = (wave >> 1) * 64, wn = (wave & 1) * 64;

    f4v acc[4][4];
#pragma unroll
    for (int i = 0; i < 4; ++i)
#pragma unroll
        for (int j = 0; j < 4; ++j) acc[i][j] = (f4v)0.f;

    float bias[4];
#pragma unroll
    for (int nt = 0; nt < 4; ++nt) {
        int n = n0 + wn + nt * 16 + lid;
        bias[nt] = (n < NGATE) ? b_f[n] : b_b[n - NGATE];
    }

    int c0 = tid, c1 = tid + 256;
    const _Float16* aptr0 = Xcat + (size_t)(m0 + (c0 >> 2)) * KPAD + (c0 & 3) * 8;
    const _Float16* aptr1 = Xcat + (size_t)(m0 + (c1 >> 2)) * KPAD + (c1 & 3) * 8;
    const _Float16* bptr0 = Wcat + (size_t)(n0 + (c0 >> 2)) * KPAD + (c0 & 3) * 8;
    const _Float16* bptr1 = Wcat + (size_t)(n0 + (c1 >> 2)) * KPAD + (c1 & 3) * 8;
    int la0 = (c0 >> 2) * LSTR + (c0 & 3) * 8;
    int la1 = (c1 >> 2) * LSTR + (c1 & 3) * 8;

    half8 ra0 = *(const half8*)(aptr0);
    half8 ra1 = *(const half8*)(aptr1);
    half8 rb0 = *(const half8*)(bptr0);
    half8 rb1 = *(const half8*)(bptr1);

    for (int k0 = 0; k0 < KPAD; k0 += 32) {
        __syncthreads();
        *(half8*)&Asub[la0] = ra0;
        *(half8*)&Asub[la1] = ra1;
        *(half8*)&Bsub[la0] = rb0;
        *(half8*)&Bsub[la1] = rb1;
        __syncthreads();
        if (k0 + 32 < KPAD) {
            ra0 = *(const half8*)(aptr0 + k0 + 32);
            ra1 = *(const half8*)(aptr1 + k0 + 32);
            rb0 = *(const half8*)(bptr0 + k0 + 32);
            rb1 = *(const half8*)(bptr1 + k0 + 32);
        }
        half8 aF[4], bF[4];
#pragma unroll
        for (int mt = 0; mt < 4; ++mt)
            aF[mt] = *(const half8*)&Asub[(wm + mt * 16 + lid) * LSTR + quad * 8];
#pragma unroll
        for (int nt = 0; nt < 4; ++nt)
            bF[nt] = *(const half8*)&Bsub[(wn + nt * 16 + lid) * LSTR + quad * 8];
#pragma unroll
        for (int mt = 0; mt < 4; ++mt)
#pragma unroll
            for (int nt = 0; nt < 4; ++nt)
                acc[mt][nt] = __builtin_amdgcn_mfma_f32_16x16x32_f16(
                    aF[mt], bF[nt], acc[mt][nt], 0, 0, 0);
    }

#pragma unroll
    for (int mt = 0; mt < 4; ++mt)
#pragma unroll
        for (int nt = 0; nt < 4; ++nt) {
            int n = n0 + wn + nt * 16 + lid;
#pragma unroll
            for (int r = 0; r < 4; ++r) {
                int m = m0 + wm + mt * 16 + quad * 4 + r;
                pre[(size_t)m * NCOLS + n] = acc[mt][nt][r] + bias[nt];
            }
        }
}

// ---------------------------------------------------------------------------
// Kernel 3: LSTM recurrence v12 — 8-problem batched MFMA + staged gates.
// 8 blocks x 512 threads.  Block: dir = blk>>2, bgrp = blk&3, probs
// b = bgrp*8 + (lid&7).  MFMA core IDENTICAL to v10 (verified-passing):
// wave wv owns h-slice [16wv,16wv+16); afr[tau][kt] = Whh rows; B cols =
// Hs rows (cols 8-15 read permanently-zero rows -> dead, harmless).
// Post-MFMA: lanes lid>=8 take over r=2,3 of column lid-8 via row_ror:8
// DPP (verified primitive) -> each lane activates exactly 2 h (8 gates,
// 20 trans) instead of 16 gates (halves the VALU tail below the 620cy
// MFMA floor).
// Gate pre-acts: NO per-lane gathers.  Double-buffered LDS stage Ps:
// 2 coalesced global_load_dwordx4/thread issued ONE STEP AHEAD (T14),
// vmcnt(0) + ds_write after compute, lanes ds_read_b64 their 4 pairs.
// One lgkm barrier per step; Hs double-buffered as v10.
// ---------------------------------------------------------------------------
#define HSTR 304   // bytes per Hs row (128 f16 + 24 pad)
#define PSTR 520   // floats per Ps row (512 gates + 8 pad)
__global__ __launch_bounds__(512, 2) void lstm_rec(
        const float* __restrict__ pre,
        const float* __restrict__ Whh_f, const float* __restrict__ Whh_b,
        float* __restrict__ pooled) {
    __shared__ __align__(16) _Float16 Hs[2 * 16 * (HSTR / 2)];
    __shared__ __align__(16) float    Ps[2 * 8 * PSTR];
    int t = threadIdx.x;
    int lane = t & 63;
    int wv = t >> 6;                 // 0..7 : h-slice [16wv, 16wv+16)
    int lid = lane & 15;
    int quad = lane >> 4;
    int p = lid & 7;                 // problem within block
    int rsel = lid >> 3;             // 0: r=0,1 ; 1: r=2,3 (of column p)
    int dir = blockIdx.x >> 2;
    int bgrp = blockIdx.x & 3;
    int b = bgrp * 8 + p;
    const float* Whh = dir ? Whh_b : Whh_f;

    // persistent A-fragments (verified v10 layout): 16 x half8
    half8 afr[4][4];
#pragma unroll
    for (int tau = 0; tau < 4; ++tau)
#pragma unroll
        for (int kt = 0; kt < 4; ++kt) {
            const float* rp = Whh + (size_t)(tau * HDIM + 16 * wv + lid) * HDIM
                            + 32 * kt + 8 * quad;
            half8 hv;
#pragma unroll
            for (int e = 0; e < 8; ++e) hv[e] = (_Float16)rp[e];
            afr[tau][kt] = hv;
        }

    // zero both Hs buffers (rows 8-15 stay zero forever -> dead B cols)
    for (int i = t; i < 2 * 16 * (HSTR / 4); i += 512) ((uint*)Hs)[i] = 0u;

    // ---- staging role: thread t covers prob sp, 16B unit su ----
    int sp = t >> 6;                 // 0..7
    int su = t & 63;                 // 0..63 (x16B)
    int s0 = dir ? (S_LEN - 1) : 0;
    long pd = dir ? -(long)NCOLS : (long)NCOLS;
    const float* gptr = pre + (size_t)((bgrp * 8 + sp) * S_LEN + s0) * NCOLS
                      + dir * NGATE + su * 4;

    f4v rg0, rg1;
    rg0 = *(const f4v*)(gptr);
    rg1 = *(const f4v*)(gptr + 256);
    gptr += pd;
    asm volatile("s_waitcnt vmcnt(0)" ::: "memory");
    {   // stage s0 into Ps buf 0
        float* pw = Ps + sp * PSTR + su * 4;
        *(f4v*)(pw) = rg0;
        *(f4v*)(pw + 256) = rg1;
    }
    rg0 = *(const f4v*)(gptr);       // s1 loads, in flight across barrier
    rg1 = *(const f4v*)(gptr + 256);
    gptr += pd;

    const f4v zero4 = (f4v)0.f;
    float cc0 = 0.f, cc1 = 0.f;
    float hm0 = -1e30f, hm1 = -1e30f;

    asm volatile("s_waitcnt lgkmcnt(0)\n\ts_barrier" ::: "memory");

    for (int step = 0; step < S_LEN; ++step) {
        int cur = step & 1;
        // gate pre-acts for this lane's 2 h (pairs per tau)
        const float* prd = Ps + cur * 8 * PSTR + p * PSTR
                         + 16 * wv + 4 * quad + rsel * 2;
        f2 Pl0 = *(const f2*)(prd);
        f2 Pl1 = *(const f2*)(prd + 128);
        f2 Pl2 = *(const f2*)(prd + 256);
        f2 Pl3 = *(const f2*)(prd + 384);

        // B-fragments: Hs row lid (verified v10 pattern)
        const char* hrd = (const char*)Hs + cur * 16 * HSTR + lid * HSTR
                        + 16 * quad;
        half8 bf0 = *(const half8*)(hrd);
        half8 bf1 = *(const half8*)(hrd + 64);
        half8 bf2 = *(const half8*)(hrd + 128);
        half8 bf3 = *(const half8*)(hrd + 192);

        f4v acc[4];
#pragma unroll
        for (int tau = 0; tau < 4; ++tau) {
            f4v a = __builtin_amdgcn_mfma_f32_16x16x32_f16(afr[tau][0], bf0, zero4, 0, 0, 0);
            a = __builtin_amdgcn_mfma_f32_16x16x32_f16(afr[tau][1], bf1, a, 0, 0, 0);
            a = __builtin_amdgcn_mfma_f32_16x16x32_f16(afr[tau][2], bf2, a, 0, 0, 0);
            a = __builtin_amdgcn_mfma_f32_16x16x32_f16(afr[tau][3], bf3, a, 0, 0, 0);
            acc[tau] = a;
        }

        // split: lanes rsel=1 take r=2,3 of column lid-8 via row_ror:8
        float g0[4], g1[4];
#pragma unroll
        for (int tau = 0; tau < 4; ++tau) {
            float m2 = dpp_mov<0x128>(acc[tau][2]);
            float m3 = dpp_mov<0x128>(acc[tau][3]);
            g0[tau] = rsel ? m2 : acc[tau][0];
            g1[tau] = rsel ? m3 : acc[tau][1];
        }
        g0[0] += Pl0[0]; g1[0] += Pl0[1];
        g0[1] += Pl1[0]; g1[1] += Pl1[1];
        g0[2] += Pl2[0]; g1[2] += Pl2[1];
        g0[3] += Pl3[0]; g1[3] += Pl3[1];

        // activations: 2 h per lane (exact math of verified kernels)
        float h0, h1;
        {
            float ii = __builtin_amdgcn_rcpf(1.f + __expf(-g0[0]));
            float ff = __builtin_amdgcn_rcpf(1.f + __expf(-g0[1]));
            float tg = fmaf(__builtin_amdgcn_rcpf(1.f + __expf(-2.f * g0[2])), 2.f, -1.f);
            float oo = __builtin_amdgcn_rcpf(1.f + __expf(-g0[3]));
            cc0 = fmaf(ff, cc0, ii * tg);
            float th = fmaf(__builtin_amdgcn_rcpf(1.f + __expf(-2.f * cc0)), 2.f, -1.f);
            h0 = oo * th;
            hm0 = fmaxf(hm0, h0);
        }
        {
            float ii = __builtin_amdgcn_rcpf(1.f + __expf(-g1[0]));
            float ff = __builtin_amdgcn_rcpf(1.f + __expf(-g1[1]));
            float tg = fmaf(__builtin_amdgcn_rcpf(1.f + __expf(-2.f * g1[2])), 2.f, -1.f);
            float oo = __builtin_amdgcn_rcpf(1.f + __expf(-g1[3]));
            cc1 = fmaf(ff, cc1, ii * tg);
            float th = fmaf(__builtin_amdgcn_rcpf(1.f + __expf(-2.f * cc1)), 2.f, -1.f);
            h1 = oo * th;
            hm1 = fmaxf(hm1, h1);
        }

        // write this lane's h-pair into next Hs buffer (row p only)
        {
            char* hwr = (char*)Hs + (cur ^ 1) * 16 * HSTR + p * HSTR
                      + (16 * wv + 4 * quad + rsel * 2) * 2;
            h2 hv;
            hv[0] = (_Float16)h0;
            hv[1] = (_Float16)h1;
            *(h2*)(hwr) = hv;
        }

        // stage next step's gates (loaded last step), then issue s+2
        asm volatile("s_waitcnt vmcnt(0)" ::: "memory");
        {
            float* pw = Ps + (cur ^ 1) * 8 * PSTR + sp * PSTR + su * 4;
            *(f4v*)(pw) = rg0;
            *(f4v*)(pw + 256) = rg1;
        }
        if (step + 2 < S_LEN) {
            rg0 = *(const f4v*)(gptr);
            rg1 = *(const f4v*)(gptr + 256);
            gptr += pd;
        }
        asm volatile("s_waitcnt lgkmcnt(0)\n\ts_barrier" ::: "memory");
    }

    {
        f2 pv;
        pv[0] = hm0;
        pv[1] = hm1;
        *(f2*)(pooled + b * 256 + dir * HDIM + 16 * wv + 4 * quad + rsel * 2) = pv;
    }
}

// ---------------------------------------------------------------------------
// Kernel 4: classifier (unchanged)
// ---------------------------------------------------------------------------
__global__ void cls_kernel(const float* __restrict__ pooled,
                           const float* __restrict__ W_cls,
                           const float* __restrict__ b_cls,
                           float* __restrict__ out) {
    int i = threadIdx.x;
    if (i < BATCH * 5) {
        int b = i / 5, l = i % 5;
        float acc = b_cls[l];
        const float* p = pooled + b * 256;
        const float* w = W_cls + l * 256;
#pragma unroll 8
        for (int j = 0; j < 256; ++j) acc = fmaf(p[j], w[j], acc);
        out[i] = acc;
    }
}

// ---------------------------------------------------------------------------
extern "C" void kernel_launch(void* const* d_in, const int* in_sizes, int n_in,
                              void* d_out, int out_size, void* d_ws, size_t ws_size,
                              hipStream_t stream) {
    const int*   word_ids   = (const int*)d_in[0];
    const int*   deps_ids   = (const int*)d_in[1];
    const float* word_table = (const float*)d_in[2];
    const float* dep_table  = (const float*)d_in[3];
    const float* Wih_f      = (const float*)d_in[4];
    const float* Whh_f      = (const float*)d_in[5];
    const float* b_f        = (const float*)d_in[6];
    const float* Wih_b      = (const float*)d_in[7];
    const float* Whh_b      = (const float*)d_in[8];
    const float* b_b        = (const float*)d_in[9];
    const float* W_cls      = (const float*)d_in[10];
    const float* b_cls      = (const float*)d_in[11];
    float* out = (float*)d_out;

    float*     pre    = (float*)d_ws;
    float*     pooled = pre + (size_t)BATCH * S_LEN * NCOLS;
    _Float16*  Xcat   = (_Float16*)(pooled + BATCH * 256);
    _Float16*  Wcat   = Xcat + (size_t)BATCH * S_LEN * KPAD;

    embed_wcat<<<BATCH * S_LEN + NCOLS, 128, 0, stream>>>(
        word_ids, deps_ids, word_table, dep_table, Wih_f, Wih_b, Xcat, Wcat);
    gemm_mfma<<<dim3(128, 8), 256, 0, stream>>>(Xcat, Wcat, b_f, b_b, pre);
    lstm_rec<<<8, 512, 0, stream>>>(pre, Whh_f, Whh_b, pooled);
    cls_kernel<<<1, 192, 0, stream>>>(pooled, W_cls, b_cls, out);
}